// Round 14
// baseline (151.953 us; speedup 1.0000x reference)
//
#include <hip/hip_runtime.h>
#include <math.h>

// ---------------------------------------------------------------------------
// MS-SSIM + MSE loss, (16,3,512,512) f32, 5 pyramid levels.
// R14 = R13 + (a) merged-ssq 4-field FIR: H-pass same 77 ops but V-pass
// 44 fma (4 chains: a, b, ab, a^2+b^2) and FIR state 44 regs;
// (b) 2 rows per barrier: 4-slot ring, iteration loads rows 2i+2/2i+3,
// computes rows 2i/2i+1, one __syncthreads (21 barriers instead of 42).
// All ROWS are even at every level -> no odd tail. Pool pair = (2i,2i+1).
// Column-streaming, 256-thread blocks, v2f (a,b) LDS (ds_read_b64).
// Bands: L0 16x32, L1 16x16, L2 16x8, L3 8x8, L4 6x4. Per-block partials,
// f64 final. DO NOT tighten launch_bounds: (256,4) is load-bearing
// (R6/R11 spilled at tighter bounds -> scratch, 2-5x slowdowns).
// ---------------------------------------------------------------------------

#define NPLANES 48

struct GaussW { float g[11]; };

typedef float v2f __attribute__((ext_vector_type(2)));

// ws float offsets: pyramids + per-BLOCK partial areas
#define PYR2_OFF  4177920
#define P_L0      8355840   // 1536 pairs
#define P_L1      8358912   // 768 pairs
#define P_L2      8360448   // 384 pairs
#define P_L3      8361216   // 96 pairs
#define P_L4      8361408   // 36 pairs
#define P_MSE     8361480   // 1536 singles

#define C1F 1.0e-4f
#define C2F 9.0e-4f

// ---------------------------------------------------------------------------
template <int LOGW, int BH, int DO_MSE, int DO_POOL>
__global__ __launch_bounds__(256, 4) void ssim_band(
    const float* __restrict__ x1, const float* __restrict__ x2, GaussW gw,
    float* __restrict__ partials, float* __restrict__ msep,
    float* __restrict__ d1, float* __restrict__ d2)
{
  constexpr int W = 1 << LOGW;
  constexpr int Ho = W - 10;
  constexpr int LOGWB = (LOGW > 8) ? 8 : LOGW;
  constexpr int WB = 1 << LOGWB;     // columns per block (per plane)
  constexpr int P = 256 >> LOGWB;    // planes per block
  constexpr int STRIDE = WB + 12;
  constexpr int W2 = W >> 1;

  // 4-slot ring, (a,b) interleaved (ds_read_b64 per tap)
  __shared__ v2f vbuf[4][P][STRIDE];
  __shared__ float red[3][4];

  const int tid = threadIdx.x;
  const int p = tid >> LOGWB;
  const int col = tid & (WB - 1);
  const int bx = blockIdx.x, by = blockIdx.y, bz = blockIdx.z;
  const int gcol = bx * WB + col;            // plane-local column
  const int plane = bz * P + p;
  const size_t pb = (size_t)plane * W * W;
  const float* q1 = x1 + pb + gcol;
  const float* q2 = x2 + pb + gcol;
  const int gr0 = BH * by;
  const int ROWS = ((W - gr0) < (BH + 10)) ? (W - gr0) : (BH + 10);  // even
  const bool xtra = (bx * WB + WB + col) < W;  // extra halo col exists

  // 4-field transposed FIR: f*[10] emits out row (R-10)
  // f1=conv(a), f2=conv(b), f3=conv(ab), f4=conv(a^2+b^2)
  float f1[11], f2[11], f3[11], f4[11];
#pragma unroll
  for (int j = 0; j < 11; ++j) { f1[j] = 0.f; f2[j] = 0.f; f3[j] = 0.f; f4[j] = 0.f; }

  float mse_acc = 0.f, ssim_acc = 0.f, cs_acc = 0.f;

#define LOADR(R, a, b, ae, be)                                          \
  {                                                                     \
    a = 0.f; b = 0.f; ae = 0.f; be = 0.f;                               \
    {                                                                   \
      size_t ro = (size_t)(gr0 + (R)) * W;                              \
      a = q1[ro]; b = q2[ro];                                           \
      if (col < 12 && xtra) { ae = q1[ro + WB]; be = q2[ro + WB]; }     \
      if (DO_MSE && (R) < BH) {                                         \
        float d_ = a - b;                                               \
        mse_acc = fmaf(d_, d_, mse_acc);                                \
      }                                                                 \
    }                                                                   \
  }

#define STAGE(R, a, b, ae, be)                                          \
  {                                                                     \
    const int sl_ = (R) & 3;                                            \
    vbuf[sl_][p][col] = (v2f){a, b};                                    \
    if (col < 12) vbuf[sl_][p][WB + col] = (v2f){ae, be};               \
  }

  // process one row R (H-pass from slot R&3, FIR shift, SSIM/CS emit)
#define PROW(R)                                                         \
  {                                                                     \
    const v2f* r_ = &vbuf[(R) & 3][p][col];                             \
    float s1 = 0.f, s2 = 0.f, s3 = 0.f, s4 = 0.f;                       \
    _Pragma("unroll") for (int k = 0; k < 11; ++k) {                    \
      v2f ab = r_[k];                                                   \
      float av = ab.x, bv = ab.y, w = gw.g[k];                          \
      float wa = w * av, wb = w * bv;                                   \
      s1 += wa; s2 += wb;                                               \
      s3 = fmaf(wa, bv, s3);                                            \
      s4 = fmaf(wa, av, s4);                                            \
      s4 = fmaf(wb, bv, s4);                                            \
    }                                                                   \
    _Pragma("unroll") for (int j = 10; j >= 1; --j) {                   \
      f1[j] = fmaf(gw.g[j], s1, f1[j - 1]);                             \
      f2[j] = fmaf(gw.g[j], s2, f2[j - 1]);                             \
      f3[j] = fmaf(gw.g[j], s3, f3[j - 1]);                             \
      f4[j] = fmaf(gw.g[j], s4, f4[j - 1]);                             \
    }                                                                   \
    f1[0] = gw.g[0] * s1;                                               \
    f2[0] = gw.g[0] * s2;                                               \
    f3[0] = gw.g[0] * s3;                                               \
    f4[0] = gw.g[0] * s4;                                               \
    if ((R) >= 10 && gcol < Ho) {                                       \
      float m1 = f1[10], m2 = f2[10], e12 = f3[10], esq = f4[10];       \
      float m12 = m1 * m2;                                              \
      float msq = fmaf(m1, m1, m2 * m2);                                \
      float v1 = 2.f * (e12 - m12) + C2F;                               \
      float vv2 = (esq - msq) + C2F;                                    \
      float csv = v1 * __builtin_amdgcn_rcpf(vv2);                      \
      cs_acc += csv;                                                    \
      ssim_acc += csv * (2.f * m12 + C1F) *                             \
                  __builtin_amdgcn_rcpf(msq + C1F);                     \
    }                                                                   \
  }

  // ---- prologue: rows 0,1 staged in slots 0,1 ----
  {
    float a0, b0, ae0, be0, a1, b1, ae1, be1;
    LOADR(0, a0, b0, ae0, be0)
    LOADR(1, a1, b1, ae1, be1)
    STAGE(0, a0, b0, ae0, be0)
    STAGE(1, a1, b1, ae1, be1)
  }
  __syncthreads();

  for (int i = 0; i < ROWS / 2; ++i) {
    const int r0 = 2 * i, r1 = 2 * i + 1;
    const bool have = (r0 + 2) < ROWS;  // ROWS even => r0+3 < ROWS too

    // issue next 2 rows' global loads early (hide HBM under compute)
    float na0 = 0.f, nb0 = 0.f, nae0 = 0.f, nbe0 = 0.f;
    float na1 = 0.f, nb1 = 0.f, nae1 = 0.f, nbe1 = 0.f;
    if (have) {
      LOADR(r0 + 2, na0, nb0, nae0, nbe0)
      LOADR(r1 + 2, na1, nb1, nae1, nbe1)
    }

    // ---- compute both resident rows ----
    PROW(r0)
    PROW(r1)

    // ---- fused 2x2 avgpool on row pair (r0, r1) ----
    if (DO_POOL && r0 < BH && col < (WB / 2)) {
      v2f x0 = vbuf[r0 & 3][p][2 * col], x1v = vbuf[r0 & 3][p][2 * col + 1];
      v2f y0 = vbuf[r1 & 3][p][2 * col], y1v = vbuf[r1 & 3][p][2 * col + 1];
      int orow = (gr0 >> 1) + i;
      size_t ob = (size_t)plane * W2 * W2 + (size_t)orow * W2 + bx * (WB / 2) + col;
      d1[ob] = 0.25f * ((x0.x + x1v.x) + (y0.x + y1v.x));
      d2[ob] = 0.25f * ((x0.y + x1v.y) + (y0.y + y1v.y));
    }

    // ---- stage next 2 rows, one barrier per 2 rows ----
    if (have) {
      STAGE(r0 + 2, na0, nb0, nae0, nbe0)
      STAGE(r1 + 2, na1, nb1, nae1, nbe1)
      __syncthreads();
    }
  }
#undef LOADR
#undef STAGE
#undef PROW

  // ---- block reduce (ssim, cs, mse) ----
#pragma unroll
  for (int off = 32; off; off >>= 1) {
    ssim_acc += __shfl_down(ssim_acc, off);
    cs_acc += __shfl_down(cs_acc, off);
    if (DO_MSE) mse_acc += __shfl_down(mse_acc, off);
  }
  int wave = tid >> 6, lane = tid & 63;
  if (lane == 0) {
    red[0][wave] = ssim_acc;
    red[1][wave] = cs_acc;
    if (DO_MSE) red[2][wave] = mse_acc;
  }
  __syncthreads();
  if (tid == 0) {
    float s = 0.f, cc = 0.f, m = 0.f;
#pragma unroll
    for (int i = 0; i < 4; ++i) {
      s += red[0][i];
      cc += red[1][i];
      if (DO_MSE) m += red[2][i];
    }
    int bi = (bz * gridDim.y + by) * gridDim.x + bx;
    partials[2 * bi] = s;
    partials[2 * bi + 1] = cc;
    if (DO_MSE) msep[bi] = m;
  }
}

// ---------------------------------------------------------------------------
__global__ __launch_bounds__(256) void final_kernel(
    const float* __restrict__ ws, float* __restrict__ out)
{
  __shared__ double sred[2][4];
  __shared__ double fin[11];  // ssim[5], cs[5], mse
  const int tid = threadIdx.x;
  const int offs[5] = {P_L0, P_L1, P_L2, P_L3, P_L4};
  const int cnts[5] = {1536, 768, 384, 96, 36};

  for (int l = 0; l < 5; ++l) {
    double s0 = 0.0, s1 = 0.0;
    for (int i = tid; i < cnts[l]; i += 256) {
      s0 += (double)ws[offs[l] + 2 * i];
      s1 += (double)ws[offs[l] + 2 * i + 1];
    }
#pragma unroll
    for (int off = 32; off; off >>= 1) {
      s0 += __shfl_down(s0, off);
      s1 += __shfl_down(s1, off);
    }
    if ((tid & 63) == 0) { sred[0][tid >> 6] = s0; sred[1][tid >> 6] = s1; }
    __syncthreads();
    if (tid == 0) {
      double aa = 0.0, bb = 0.0;
      for (int i = 0; i < 4; ++i) { aa += sred[0][i]; bb += sred[1][i]; }
      fin[l] = aa;
      fin[5 + l] = bb;
    }
    __syncthreads();
  }

  {
    double s0 = 0.0;
    for (int i = tid; i < 1536; i += 256) s0 += (double)ws[P_MSE + i];
#pragma unroll
    for (int off = 32; off; off >>= 1) s0 += __shfl_down(s0, off);
    if ((tid & 63) == 0) sred[0][tid >> 6] = s0;
    __syncthreads();
    if (tid == 0) {
      double aa = 0.0;
      for (int i = 0; i < 4; ++i) aa += sred[0][i];
      fin[10] = aa;
    }
    __syncthreads();
  }

  if (tid == 0) {
    const double wts[5] = {0.0448, 0.2856, 0.3001, 0.2363, 0.1333};
    const double dims[5] = {502.0, 246.0, 118.0, 54.0, 22.0};
    double mssim[5], mcs[5];
    for (int l = 0; l < 5; ++l) {
      double n = 48.0 * dims[l] * dims[l];
      mssim[l] = fin[l] / n;
      mcs[l] = fin[5 + l] / n;
    }
    // literal pytorch_msssim translation: prod(pow1[:-1] * pow2[-1])
    double p2last = pow(mssim[4], wts[4]);
    double prod = 1.0;
    for (int i = 0; i < 4; ++i) prod *= pow(mcs[i], wts[i]) * p2last;
    double msssim = prod;
    double mse = fin[10] / 12582912.0;
    out[0] = (float)(mse - msssim + 1.0);
    out[1] = (float)msssim;
  }
}

// ---------------------------------------------------------------------------
extern "C" void kernel_launch(void* const* d_in, const int* in_sizes, int n_in,
                              void* d_out, int out_size, void* d_ws, size_t ws_size,
                              hipStream_t stream)
{
  const float* rec = (const float*)d_in[0];   // reconst
  const float* orig = (const float*)d_in[1];  // original
  float* ws = (float*)d_ws;
  float* out = (float*)d_out;

  GaussW gw;
  {
    double g[11], s = 0.0;
    for (int i = 0; i < 11; ++i) {
      double x = (double)i - 5.0;
      g[i] = exp(-(x * x) / 4.5);
      s += g[i];
    }
    for (int i = 0; i < 11; ++i) gw.g[i] = (float)(g[i] / s);
  }

  // pyramid pointers
  float* A1 = ws + 0;
  float* A2 = ws + 3145728;
  float* A3 = ws + 3932160;
  float* A4 = ws + 4128768;
  float* B1 = ws + PYR2_OFF;
  float* B2 = ws + PYR2_OFF + 3145728;
  float* B3 = ws + PYR2_OFF + 3932160;
  float* B4 = ws + PYR2_OFF + 4128768;

  // grid = (col strips, bands, planes/P); band heights tuned per level
  ssim_band<9, 32, 1, 1><<<dim3(2, 16, 48), 256, 0, stream>>>(
      orig, rec, gw, ws + P_L0, ws + P_MSE, A1, B1);    // 1536 blocks
  ssim_band<8, 16, 0, 1><<<dim3(1, 16, 48), 256, 0, stream>>>(
      A1, B1, gw, ws + P_L1, nullptr, A2, B2);          // 768 blocks
  ssim_band<7, 8, 0, 1><<<dim3(1, 16, 24), 256, 0, stream>>>(
      A2, B2, gw, ws + P_L2, nullptr, A3, B3);          // 384 blocks
  ssim_band<6, 8, 0, 1><<<dim3(1, 8, 12), 256, 0, stream>>>(
      A3, B3, gw, ws + P_L3, nullptr, A4, B4);          // 96 blocks
  ssim_band<5, 4, 0, 0><<<dim3(1, 6, 6), 256, 0, stream>>>(
      A4, B4, gw, ws + P_L4, nullptr, nullptr, nullptr); // 36 blocks

  final_kernel<<<dim3(1), dim3(256), 0, stream>>>(ws, out);
}